// Round 10
// baseline (114.987 us; speedup 1.0000x reference)
//
#include <hip/hip_runtime.h>

typedef unsigned int u32;

// ---------------- FFT-based reverb (R10: radix-4, swizzled LDS) ----------------
// out[t] = sum_k audio[t+k] ir[k], t in [0,480000); M = 2^20 circular == linear.
// z = a + i*b ; Z = F[z]; A=(Z[f]+conj(Z[M-f]))/2, B=(Z[f]-conj(Z[M-f]))/(2i)
// S = A*conj(B); out = Re( F[ conj(S)/M ] ).
// Four-step M = 1024*1024 (verified R8/R9); radix-4 Stockham FFT-1024 in LDS.

constexpr int N_AUDIO = 480000;
constexpr int K_IR    = 240000;
constexpr int M_FFT   = 1048576;      // 2^20

constexpr size_t OFF_C0   = 0;                    // 8 MB float2
constexpr size_t OFF_C1   = (size_t)M_FFT * 8;    // 8 MB float2
constexpr size_t OFF_SLOT = OFF_C1 + (size_t)M_FFT * 8;   // u32

#define SW(i) ((i) + ((i) >> 4))      // LDS pad swizzle: kills 16-way scatter conflicts
constexpr int LSZ = 1088;             // SW(1023)=1086

__device__ __forceinline__ float2 cmul(float2 a, float2 b) {
    return make_float2(a.x * b.x - a.y * b.y, a.x * b.y + a.y * b.x);
}
__device__ __forceinline__ float2 twid(float frac) {   // e^{-2*pi*i*frac}
    float s, c;
    __sincosf(-6.28318530717958647692f * frac, &s, &c);
    return make_float2(c, s);
}
// tw[P+k] = e^{-2*pi*i*k/(2P)}, P=1..512 pow2, k<P (1023 entries)
__device__ __forceinline__ void build_tw(float2* tw, int t) {
    #pragma unroll
    for (int i = t + 1; i < 1024; i += 256) {
        int L = 1 << (31 - __builtin_clz(i));
        tw[i] = twid((float)(i - L) / (float)(2 * L));
    }
}

// Radix-4 Stockham FFT-1024, NB rows, 256 threads, 5 stages, result in B0.
// Derived from two composed radix-2 stages (R8-verified); n=4 hand-checked.
template<int NB>
__device__ __forceinline__ void fft1024_r4(float2 (*A0)[LSZ], float2 (*B0)[LSZ],
                                           const float2* tw, int t) {
    float2 (*A)[LSZ] = A0;
    float2 (*B)[LSZ] = B0;
    #pragma unroll
    for (int s = 0; s < 5; ++s) {
        const int L  = 1 << (2 * s);
        const int k  = t & (L - 1);
        const int p0 = 4 * t - 3 * k;
        const float2 w  = tw[L + k];
        const float2 w2 = tw[2 * L + k];
        #pragma unroll
        for (int j = 0; j < NB; ++j) {
            float2 x0 = A[j][SW(t)];
            float2 x2 = A[j][SW(t + 256)];
            float2 x1 = A[j][SW(t + 512)];
            float2 x3 = A[j][SW(t + 768)];
            float2 wx1 = cmul(w, x1), wx3 = cmul(w, x3);
            float2 u0 = make_float2(x0.x + wx1.x, x0.y + wx1.y);
            float2 u1 = make_float2(x0.x - wx1.x, x0.y - wx1.y);
            float2 u2 = make_float2(x2.x + wx3.x, x2.y + wx3.y);
            float2 u3 = make_float2(x2.x - wx3.x, x2.y - wx3.y);
            float2 a2 = cmul(w2, u2);
            float2 a3 = cmul(w2, u3);
            B[j][SW(p0)]         = make_float2(u0.x + a2.x, u0.y + a2.y);
            B[j][SW(p0 + L)]     = make_float2(u1.x + a3.y, u1.y - a3.x); // u1 - i*a3
            B[j][SW(p0 + 2*L)]   = make_float2(u0.x - a2.x, u0.y - a2.y);
            B[j][SW(p0 + 3*L)]   = make_float2(u1.x - a3.y, u1.y + a3.x); // u1 + i*a3
        }
        __syncthreads();
        float2 (*tmp)[LSZ] = A; A = B; B = tmp;
    }
}

// ---- kernel A: transform-1 pass1 + input pack. 1 row r=blockIdx, grid 1024.
__global__ __launch_bounds__(256) void fft1_p1(const float* __restrict__ a,
                                               const float* __restrict__ b,
                                               float2* __restrict__ outb,
                                               u32* __restrict__ slot) {
    __shared__ float2 rows[1][LSZ], scr[1][LSZ], tw[1024];
    const int t = threadIdx.x;
    const int r = blockIdx.x;
    if (r == 0 && t == 0) *slot = 0u;
    build_tw(tw, t);
    #pragma unroll
    for (int q = 0; q < 4; ++q) {
        int c = t + 256 * q;
        int idx = c * 1024 + r;
        float av = (idx < N_AUDIO) ? a[idx] : 0.0f;
        float bv = (idx < K_IR)    ? b[idx] : 0.0f;
        rows[0][SW(c)] = make_float2(av, bv);
    }
    __syncthreads();
    fft1024_r4<1>(rows, scr, tw, t);
    const float fr = (float)r * (1.0f / 1048576.0f);
    #pragma unroll
    for (int q = 0; q < 4; ++q) {
        int k1 = t + 256 * q;
        outb[r * 1024 + k1] = cmul(twid(fr * (float)k1), scr[0][SW(k1)]);
    }
}

// ---- kernel B: transform-1 pass2 + pointwise. Hermitian column pair per block.
// block 0 -> {0,512} (self-paired), block b -> {b, 1024-b}. grid 512.
__global__ __launch_bounds__(256) void fft1_p2_pw(const float2* __restrict__ in,
                                                  float2* __restrict__ spec) {
    __shared__ float2 cols[2][LSZ], scr[2][LSZ], tw[1024];
    const int t = threadIdx.x;
    const int bidx = blockIdx.x;
    const int cA = (bidx == 0) ? 0   : bidx;
    const int cB = (bidx == 0) ? 512 : 1024 - bidx;
    build_tw(tw, t);
    #pragma unroll
    for (int q = 0; q < 4; ++q) {
        int r = t + 256 * q;
        cols[0][SW(r)] = in[r * 1024 + cA];
        cols[1][SW(r)] = in[r * 1024 + cB];
    }
    __syncthreads();
    fft1024_r4<2>(cols, scr, tw, t);
    const float invM = 1.0f / 1048576.0f;
    #pragma unroll
    for (int q = 0; q < 4; ++q) {
        int k2 = t + 256 * q;
        #pragma unroll
        for (int j = 0; j < 2; ++j) {
            float2 z1 = scr[j][SW(k2)];                 // Z[f], f = c_j + 1024*k2
            float2 z2;                                  // Z[M-f]
            if (bidx == 0) z2 = (j == 0) ? scr[0][SW((1024 - k2) & 1023)]
                                         : scr[1][SW(1023 - k2)];
            else           z2 = scr[j ^ 1][SW(1023 - k2)];
            float2 Af  = make_float2(0.5f * (z1.x + z2.x), 0.5f * (z1.y - z2.y));
            float2 cBf = make_float2(0.5f * (z1.y + z2.y), 0.5f * (z1.x - z2.x)); // conj(B)
            float2 S   = cmul(Af, cBf);
            int cc = (j == 0) ? cA : cB;
            spec[cc * 1024 + k2] = make_float2(S.x * invM, -S.y * invM);  // conj(S)/M
        }
    }
}

// ---- kernel C: transform-2 pass1 (contiguous rows of s-layout). grid 1024.
__global__ __launch_bounds__(256) void fft2_p1(const float2* __restrict__ in,
                                               float2* __restrict__ outb) {
    __shared__ float2 rows[1][LSZ], scr[1][LSZ], tw[1024];
    const int t = threadIdx.x;
    const int r = blockIdx.x;
    build_tw(tw, t);
    #pragma unroll
    for (int q = 0; q < 4; ++q) {
        int c = t + 256 * q;
        rows[0][SW(c)] = in[r * 1024 + c];
    }
    __syncthreads();
    fft1024_r4<1>(rows, scr, tw, t);
    const float fr = (float)r * (1.0f / 1048576.0f);
    #pragma unroll
    for (int q = 0; q < 4; ++q) {
        int k1 = t + 256 * q;
        outb[r * 1024 + k1] = cmul(twid(fr * (float)k1), scr[0][SW(k1)]);
    }
}

// ---- kernel D: transform-2 pass2, column c = blockIdx; Re(out) + abs-max. grid 1024.
__global__ __launch_bounds__(256) void fft2_p2(const float2* __restrict__ in,
                                               float* __restrict__ raw,
                                               u32* __restrict__ slot) {
    __shared__ float2 cols[1][LSZ], scr[1][LSZ], tw[1024];
    __shared__ float wmax[4];
    const int t = threadIdx.x;
    const int c = blockIdx.x;
    build_tw(tw, t);
    #pragma unroll
    for (int q = 0; q < 4; ++q) {
        int r = t + 256 * q;
        cols[0][SW(r)] = in[r * 1024 + c];
    }
    __syncthreads();
    fft1024_r4<1>(cols, scr, tw, t);
    float m = 0.0f;
    #pragma unroll
    for (int q = 0; q < 4; ++q) {
        int k2 = t + 256 * q;
        int ot = c + (k2 << 10);
        if (ot < N_AUDIO) {
            float v = scr[0][SW(k2)].x;
            raw[ot] = v;
            m = fmaxf(m, fabsf(v));
        }
    }
    for (int off = 32; off > 0; off >>= 1) m = fmaxf(m, __shfl_down(m, off, 64));
    if ((t & 63) == 0) wmax[t >> 6] = m;
    __syncthreads();
    if (t == 0) {
        float bm = fmaxf(fmaxf(wmax[0], wmax[1]), fmaxf(wmax[2], wmax[3]));
        atomicMax(slot, __float_as_uint(bm));
    }
}

// ---- kernel E: normalize
__global__ __launch_bounds__(256) void scale_k(const float* __restrict__ raw,
                                               const u32* __restrict__ slot,
                                               float* __restrict__ out) {
    int i = blockIdx.x * 256 + threadIdx.x;
    if (i < N_AUDIO) out[i] = raw[i] / __uint_as_float(*slot);
}

extern "C" void kernel_launch(void* const* d_in, const int* in_sizes, int n_in,
                              void* d_out, int out_size, void* d_ws, size_t ws_size,
                              hipStream_t stream) {
    const float* audio = (const float*)d_in[0];
    const float* ir    = (const float*)d_in[1];
    float* out = (float*)d_out;

    char* ws = (char*)d_ws;
    float2* cb0 = (float2*)(ws + OFF_C0);
    float2* cb1 = (float2*)(ws + OFF_C1);
    u32*    slot = (u32*)(ws + OFF_SLOT);

    fft1_p1<<<1024, 256, 0, stream>>>(audio, ir, cb1, slot);       // pack + rows
    fft1_p2_pw<<<512, 256, 0, stream>>>(cb1, cb0);                 // cols + pointwise
    fft2_p1<<<1024, 256, 0, stream>>>(cb0, cb1);                   // rows
    fft2_p2<<<1024, 256, 0, stream>>>(cb1, (float*)cb0, slot);     // cols + absmax
    scale_k<<<1875, 256, 0, stream>>>((const float*)cb0, slot, out);
}

// Round 11
// 109.351 us; speedup vs baseline: 1.0515x; 1.0515x over previous
//
#include <hip/hip_runtime.h>

typedef unsigned int u32;

// ---------------- FFT-based reverb (R11: ROM twiddles, all-wide IO) ----------------
// out[t] = sum_k audio[t+k] ir[k], t in [0,480000); M = 2^20 circular == linear.
// z = a + i*b ; Z = F[z]; A=(Z[f]+conj(Z[M-f]))/2, B=(Z[f]-conj(Z[M-f]))/(2i)
// S = A*conj(B); out = Re( F[ conj(S)/M ] ).
// Four-step M = 1024*1024 (verified R8-R10); radix-4 swizzled Stockham in LDS.
// All twiddles from compile-time ROM tables: T1[j]=W_1024^j, T2[j]=W_M^j;
// stage tw = T1[k<<(9-2s)], T1[k<<(8-2s)]; W_M^e = T1[e>>10]*T2[e&1023].

constexpr int N_AUDIO = 480000;
constexpr int K_IR    = 240000;
constexpr int M_FFT   = 1048576;      // 2^20

constexpr size_t OFF_C0   = 0;                    // 8 MB float2
constexpr size_t OFF_C1   = (size_t)M_FFT * 8;    // 8 MB float2
constexpr size_t OFF_SLOT = OFF_C1 + (size_t)M_FFT * 8;   // u32

#define SW(i) ((i) + ((i) >> 4))      // LDS pad swizzle
constexpr int LSZ = 1088;             // SW(1023)=1086

// ---- compile-time twiddle ROM (constexpr Taylor, double precision) ----
struct F2 { float x, y; };
constexpr double D_PI = 3.14159265358979323846264338327950288;
constexpr double tay_sin(double x) {
    double t = x, s = x, x2 = x * x;
    for (int k = 1; k <= 11; ++k) { t *= -x2 / (double)((2 * k) * (2 * k + 1)); s += t; }
    return s;
}
constexpr double tay_cos(double x) {
    double t = 1.0, s = 1.0, x2 = x * x;
    for (int k = 1; k <= 11; ++k) { t *= -x2 / (double)((2 * k - 1) * (2 * k)); s += t; }
    return s;
}
struct Tab { F2 v[1024]; };
constexpr Tab make_t1() {   // W_1024^j, arg centered to [-pi,pi) for accuracy
    Tab tb{};
    for (int j = 0; j < 1024; ++j) {
        int jj = (j < 512) ? j : j - 1024;
        double a = -2.0 * D_PI * (double)jj / 1024.0;
        tb.v[j] = F2{(float)tay_cos(a), (float)tay_sin(a)};
    }
    return tb;
}
constexpr Tab make_t2() {   // W_M^j, tiny args
    Tab tb{};
    for (int j = 0; j < 1024; ++j) {
        double a = -2.0 * D_PI * (double)j / 1048576.0;
        tb.v[j] = F2{(float)tay_cos(a), (float)tay_sin(a)};
    }
    return tb;
}
__device__ constexpr Tab ROM_T1 = make_t1();
__device__ constexpr Tab ROM_T2 = make_t2();

__device__ __forceinline__ float2 ldrom(const Tab& tb, int i) {
    F2 f = tb.v[i];
    return make_float2(f.x, f.y);
}
__device__ __forceinline__ float2 cmul(float2 a, float2 b) {
    return make_float2(a.x * b.x - a.y * b.y, a.x * b.y + a.y * b.x);
}

// Radix-4 Stockham FFT-1024, NB rows, 256 threads, 5 stages, result in B0 (scr).
// Identical butterfly to R10 (validated); twiddles from LDS-staged T1.
template<int NB>
__device__ __forceinline__ void fft1024_r4(float2 (*A0)[LSZ], float2 (*B0)[LSZ],
                                           const float2* lt1, int t) {
    float2 (*A)[LSZ] = A0;
    float2 (*B)[LSZ] = B0;
    #pragma unroll
    for (int s = 0; s < 5; ++s) {
        const int L  = 1 << (2 * s);
        const int k  = t & (L - 1);
        const int p0 = 4 * t - 3 * k;
        const float2 w  = lt1[k << (9 - 2 * s)];   // e^{-2pi i k/(2L)}
        const float2 w2 = lt1[k << (8 - 2 * s)];   // e^{-2pi i k/(4L)}
        #pragma unroll
        for (int j = 0; j < NB; ++j) {
            float2 x0 = A[j][SW(t)];
            float2 x2 = A[j][SW(t + 256)];
            float2 x1 = A[j][SW(t + 512)];
            float2 x3 = A[j][SW(t + 768)];
            float2 wx1 = cmul(w, x1), wx3 = cmul(w, x3);
            float2 u0 = make_float2(x0.x + wx1.x, x0.y + wx1.y);
            float2 u1 = make_float2(x0.x - wx1.x, x0.y - wx1.y);
            float2 u2 = make_float2(x2.x + wx3.x, x2.y + wx3.y);
            float2 u3 = make_float2(x2.x - wx3.x, x2.y - wx3.y);
            float2 a2 = cmul(w2, u2);
            float2 a3 = cmul(w2, u3);
            B[j][SW(p0)]         = make_float2(u0.x + a2.x, u0.y + a2.y);
            B[j][SW(p0 + L)]     = make_float2(u1.x + a3.y, u1.y - a3.x); // u1 - i*a3
            B[j][SW(p0 + 2*L)]   = make_float2(u0.x - a2.x, u0.y - a2.y);
            B[j][SW(p0 + 3*L)]   = make_float2(u1.x - a3.y, u1.y + a3.x); // u1 + i*a3
        }
        __syncthreads();
        float2 (*tmp)[LSZ] = A; A = B; B = tmp;
    }
}

// ---- kernel A: transform-1 pass1 + input pack. 2 rows/block, grid 512.
__global__ __launch_bounds__(256) void fft1_p1(const float* __restrict__ a,
                                               const float* __restrict__ b,
                                               float2* __restrict__ outb,
                                               u32* __restrict__ slot) {
    __shared__ float2 rows[2][LSZ], scr[2][LSZ], lt1[1024], lt2[1024];
    const int t  = threadIdx.x;
    const int r0 = blockIdx.x * 2;
    if (blockIdx.x == 0 && t == 0) *slot = 0u;
    #pragma unroll
    for (int q = 0; q < 4; ++q) {
        int i = t + 256 * q;
        lt1[i] = ldrom(ROM_T1, i);
        lt2[i] = ldrom(ROM_T2, i);
    }
    #pragma unroll
    for (int q = 0; q < 4; ++q) {
        int c = t + 256 * q;
        int base = c * 1024 + r0;
        float2 av = make_float2(0.f, 0.f), bv = make_float2(0.f, 0.f);
        if (c < 468 || (c == 468 && r0 < 768)) av = *(const float2*)(a + base);
        if (c < 234 || (c == 234 && r0 < 384)) bv = *(const float2*)(b + base);
        rows[0][SW(c)] = make_float2(av.x, bv.x);
        rows[1][SW(c)] = make_float2(av.y, bv.y);
    }
    __syncthreads();
    fft1024_r4<2>(rows, scr, lt1, t);
    #pragma unroll
    for (int q = 0; q < 4; ++q) {
        int k1 = t + 256 * q;
        #pragma unroll
        for (int j = 0; j < 2; ++j) {
            int e = (r0 + j) * k1;                       // < 2^20
            float2 w = cmul(lt1[e >> 10], lt2[e & 1023]); // W_M^e
            outb[(r0 + j) * 1024 + k1] = cmul(w, scr[j][SW(k1)]);
        }
    }
}

// ---- kernel B: transform-1 pass2 + pointwise. Hermitian pair {b, 1024-b}. grid 512.
__global__ __launch_bounds__(256) void fft1_p2_pw(const float2* __restrict__ in,
                                                  float2* __restrict__ spec) {
    __shared__ float2 cols[2][LSZ], scr[2][LSZ], lt1[1024];
    const int t = threadIdx.x;
    const int bidx = blockIdx.x;
    const int cA = (bidx == 0) ? 0   : bidx;
    const int cB = (bidx == 0) ? 512 : 1024 - bidx;
    #pragma unroll
    for (int q = 0; q < 4; ++q) { int i = t + 256 * q; lt1[i] = ldrom(ROM_T1, i); }
    #pragma unroll
    for (int q = 0; q < 4; ++q) {
        int r = t + 256 * q;
        cols[0][SW(r)] = in[r * 1024 + cA];
        cols[1][SW(r)] = in[r * 1024 + cB];
    }
    __syncthreads();
    fft1024_r4<2>(cols, scr, lt1, t);
    const float invM = 1.0f / 1048576.0f;
    #pragma unroll
    for (int q = 0; q < 4; ++q) {
        int k2 = t + 256 * q;
        #pragma unroll
        for (int j = 0; j < 2; ++j) {
            float2 z1 = scr[j][SW(k2)];                 // Z[f], f = c_j + 1024*k2
            float2 z2;                                  // Z[M-f]
            if (bidx == 0) z2 = (j == 0) ? scr[0][SW((1024 - k2) & 1023)]
                                         : scr[1][SW(1023 - k2)];
            else           z2 = scr[j ^ 1][SW(1023 - k2)];
            float2 Af  = make_float2(0.5f * (z1.x + z2.x), 0.5f * (z1.y - z2.y));
            float2 cBf = make_float2(0.5f * (z1.y + z2.y), 0.5f * (z1.x - z2.x)); // conj(B)
            float2 S   = cmul(Af, cBf);
            int cc = (j == 0) ? cA : cB;
            spec[cc * 1024 + k2] = make_float2(S.x * invM, -S.y * invM);  // conj(S)/M
        }
    }
}

// ---- kernel C: transform-2 pass1 (contiguous s-layout rows, float4). 2 rows/block, grid 512.
__global__ __launch_bounds__(256) void fft2_p1(const float2* __restrict__ in,
                                               float2* __restrict__ outb) {
    __shared__ float2 rows[2][LSZ], scr[2][LSZ], lt1[1024], lt2[1024];
    const int t  = threadIdx.x;
    const int r0 = blockIdx.x * 2;
    #pragma unroll
    for (int q = 0; q < 4; ++q) {
        int i = t + 256 * q;
        lt1[i] = ldrom(ROM_T1, i);
        lt2[i] = ldrom(ROM_T2, i);
    }
    const float4* inv4 = (const float4*)(in + (size_t)r0 * 1024);
    #pragma unroll
    for (int q = 0; q < 4; ++q) {
        int i2 = t + 256 * q;               // complex 2*i2, 2*i2+1
        float4 v = inv4[i2];
        int j = i2 >> 9, c = (i2 & 511) * 2;
        rows[j][SW(c)]     = make_float2(v.x, v.y);
        rows[j][SW(c + 1)] = make_float2(v.z, v.w);
    }
    __syncthreads();
    fft1024_r4<2>(rows, scr, lt1, t);
    #pragma unroll
    for (int q = 0; q < 4; ++q) {
        int k1 = t + 256 * q;
        #pragma unroll
        for (int j = 0; j < 2; ++j) {
            int e = (r0 + j) * k1;
            float2 w = cmul(lt1[e >> 10], lt2[e & 1023]);
            outb[(r0 + j) * 1024 + k1] = cmul(w, scr[j][SW(k1)]);
        }
    }
}

// ---- kernel D: transform-2 pass2, adjacent col pair {2b,2b+1} via float4 gather;
// writes TRANSPOSED scratch rawT[c*512 + k2] (contiguous) + abs-max. grid 512.
__global__ __launch_bounds__(256) void fft2_p2(const float2* __restrict__ in,
                                               float* __restrict__ rawT,
                                               u32* __restrict__ slot) {
    __shared__ float2 cols[2][LSZ], scr[2][LSZ], lt1[1024];
    __shared__ float wmax[4];
    const int t  = threadIdx.x;
    const int c0 = blockIdx.x * 2;
    #pragma unroll
    for (int q = 0; q < 4; ++q) { int i = t + 256 * q; lt1[i] = ldrom(ROM_T1, i); }
    #pragma unroll
    for (int q = 0; q < 4; ++q) {
        int r = t + 256 * q;
        float4 v = *(const float4*)(in + (size_t)r * 1024 + c0);
        cols[0][SW(r)] = make_float2(v.x, v.y);
        cols[1][SW(r)] = make_float2(v.z, v.w);
    }
    __syncthreads();
    fft1024_r4<2>(cols, scr, lt1, t);
    float m = 0.0f;
    #pragma unroll
    for (int q = 0; q < 4; ++q) {
        int k2 = t + 256 * q;
        #pragma unroll
        for (int j = 0; j < 2; ++j) {
            int ot = c0 + j + (k2 << 10);
            if (ot < N_AUDIO) {
                float v = scr[j][SW(k2)].x;
                rawT[(c0 + j) * 512 + k2] = v;       // contiguous along k2
                m = fmaxf(m, fabsf(v));
            }
        }
    }
    for (int off = 32; off > 0; off >>= 1) m = fmaxf(m, __shfl_down(m, off, 64));
    if ((t & 63) == 0) wmax[t >> 6] = m;
    __syncthreads();
    if (t == 0) {
        float bm = fmaxf(fmaxf(wmax[0], wmax[1]), fmaxf(wmax[2], wmax[3]));
        atomicMax(slot, __float_as_uint(bm));
    }
}

// ---- kernel E: tiled transpose + normalize. 64x64 tiles, coalesced both sides.
__global__ __launch_bounds__(256) void scale_t(const float* __restrict__ rawT,
                                               const u32* __restrict__ slot,
                                               float* __restrict__ out) {
    __shared__ float tile[64][65];
    const int t  = threadIdx.x;
    const int c0 = (blockIdx.x & 15) * 64;        // 16 c-tiles
    const int k0 = (blockIdx.x >> 4) * 64;        // 8 k2-tiles
    const int cl = t >> 2, ch = (t & 3) * 16;
    #pragma unroll
    for (int i = 0; i < 4; ++i) {
        float4 v = *(const float4*)(rawT + (size_t)(c0 + cl) * 512 + k0 + ch + i * 4);
        tile[cl][ch + i * 4 + 0] = v.x;
        tile[cl][ch + i * 4 + 1] = v.y;
        tile[cl][ch + i * 4 + 2] = v.z;
        tile[cl][ch + i * 4 + 3] = v.w;
    }
    __syncthreads();
    const float inv = 1.0f / __uint_as_float(*slot);
    const int cw = t & 63, w = t >> 6;
    #pragma unroll
    for (int q = 0; q < 16; ++q) {
        int kk = q * 4 + w;
        int o = (k0 + kk) * 1024 + c0 + cw;
        if (o < N_AUDIO) out[o] = tile[cw][kk] * inv;
    }
}

extern "C" void kernel_launch(void* const* d_in, const int* in_sizes, int n_in,
                              void* d_out, int out_size, void* d_ws, size_t ws_size,
                              hipStream_t stream) {
    const float* audio = (const float*)d_in[0];
    const float* ir    = (const float*)d_in[1];
    float* out = (float*)d_out;

    char* ws = (char*)d_ws;
    float2* cb0 = (float2*)(ws + OFF_C0);
    float2* cb1 = (float2*)(ws + OFF_C1);
    u32*    slot = (u32*)(ws + OFF_SLOT);

    fft1_p1<<<512, 256, 0, stream>>>(audio, ir, cb1, slot);        // pack + rows
    fft1_p2_pw<<<512, 256, 0, stream>>>(cb1, cb0);                 // cols + pointwise
    fft2_p1<<<512, 256, 0, stream>>>(cb0, cb1);                    // rows
    fft2_p2<<<512, 256, 0, stream>>>(cb1, (float*)cb0, slot);      // cols + absmax -> rawT
    scale_t<<<128, 256, 0, stream>>>((const float*)cb0, slot, out);
}